// Round 1
// baseline (449.432 us; speedup 1.0000x reference)
//
#include <hip/hip_runtime.h>
#include <math.h>

#define NLEV 24
#define CAPM 262144
#define HID 32

// ws layout: [0..23] = 1/scale (fp32-rounded like reference), [24..47] = c2f window
__global__ void init_consts(const int* __restrict__ iter_p, float* __restrict__ ws) {
    int l = threadIdx.x;
    if (l >= NLEV) return;
    double scale;
    if (l == 0) scale = 1.0;
    else if (l == NLEV - 1) scale = 0.0001;
    else scale = pow(10.0, -((double)(4 * l)) / 23.0);
    float scale_f = (float)scale;                 // reference casts geomspace to fp32
    ws[l] = (float)(1.0 / (double)scale_f);       // correctly-rounded fp32 reciprocal
    float t = (float)iter_p[0] / 10000.0f;
    t = fminf(fmaxf(t, 0.0f), 1.0f);
    float alpha = (0.3f + 0.7f * t) * 24.0f;
    float x = fminf(fmaxf(alpha - (float)l, 0.0f), 1.0f);
    ws[NLEV + l] = 0.5f * (1.0f - (float)cos(M_PI * (double)x));
}

__device__ __forceinline__ float gelu_exact(float v) {
    return 0.5f * v * (1.0f + erff(v * 0.70710678118654752f));
}

__global__ __launch_bounds__(256)
void sdf_fused(const float* __restrict__ points,
               const float* __restrict__ tables,
               const float* __restrict__ shifts,
               const float* __restrict__ w1, const float* __restrict__ b1,
               const float* __restrict__ w2, const float* __restrict__ b2,
               const float* __restrict__ w3, const float* __restrict__ b3,
               const float* __restrict__ w4, const float* __restrict__ b4,
               const float* __restrict__ cons,
               float* __restrict__ out, int N)
{
    const float SF0 = 2.3094010767585034f;  // 4/sqrt(3)
    const float SF1 = 1.3333333333333333f;  // 4/3
    const float SF2 = 0.9428090415820634f;  // 2*sqrt(2)/3

    int pid = blockIdx.x * blockDim.x + threadIdx.x;
    if (pid >= N) return;

    float px = points[3 * pid + 0];
    float py = points[3 * pid + 1];
    float pz = points[3 * pid + 2];

    // h1 = b1 + (points*0.001) @ w1[48:51,:]  (encoding levels accumulate below)
    float h1[HID];
    float cx = px * 0.001f, cy = py * 0.001f, cz = pz * 0.001f;
    #pragma unroll
    for (int j = 0; j < HID; j++) {
        float v = b1[j];
        v = fmaf(cx, w1[48 * HID + j], v);
        v = fmaf(cy, w1[49 * HID + j], v);
        v = fmaf(cz, w1[50 * HID + j], v);
        h1[j] = v;
    }

    #pragma unroll 2
    for (int l = 0; l < NLEV; l++) {
        float win = cons[NLEV + l];
        if (win == 0.0f) continue;   // exact: feature contribution is *win
        float inv = cons[l];
        float p0 = fmaf(px, inv, shifts[3 * l + 0]);
        float p1 = fmaf(py, inv, shifts[3 * l + 1]);
        float p2 = fmaf(pz, inv, shifts[3 * l + 2]);
        float c0 = p0 * SF0, c1 = p1 * SF1, c2 = p2 * SF2;
        // suffix sums -> elevated (VD=4)
        float s1 = c1 + c2;
        float s0 = c0 + s1;
        float e0 = s0;
        float e1 = s1 - c0;
        float e2 = c2 - 2.0f * c1;
        float e3 = -3.0f * c2;
        // nearest lattice remainder-0 point (round half-even like jnp.round)
        float r0f = rintf(e0 * 0.25f) * 4.0f;
        float r1f = rintf(e1 * 0.25f) * 4.0f;
        float r2f = rintf(e2 * 0.25f) * 4.0f;
        float r3f = rintf(e3 * 0.25f) * 4.0f;
        int sum_ = (int)rintf((r0f + r1f + r2f + r3f) * 0.25f);
        float d0 = e0 - r0f, d1 = e1 - r1f, d2 = e2 - r2f, d3 = e3 - r3f;
        // rank = position in stable descending sort of diff
        int k0 = (int)(d1 > d0) + (int)(d2 > d0) + (int)(d3 > d0) + sum_;
        int k1 = (int)(d0 > d1) + (int)(d2 > d1) + (int)(d3 > d1)
               + (int)(d0 == d1) + sum_;
        int k2 = (int)(d0 > d2) + (int)(d1 > d2) + (int)(d3 > d2)
               + (int)(d0 == d2) + (int)(d1 == d2) + sum_;
        int k3 = (int)(d0 > d3) + (int)(d1 > d3) + (int)(d2 > d3)
               + (int)(d0 == d3) + (int)(d1 == d3) + (int)(d2 == d3) + sum_;
        // single wrap into [0,3], adjust rem0 accordingly
        int a0 = (k0 < 0) ? 4 : ((k0 > 3) ? -4 : 0); k0 += a0; r0f += (float)a0;
        int a1 = (k1 < 0) ? 4 : ((k1 > 3) ? -4 : 0); k1 += a1; r1f += (float)a1;
        int a2 = (k2 < 0) ? 4 : ((k2 > 3) ? -4 : 0); k2 += a2; r2f += (float)a2;
        int a3 = (k3 < 0) ? 4 : ((k3 > 3) ? -4 : 0); k3 += a3; r3f += (float)a3;

        float dl0 = (e0 - r0f) * 0.25f;
        float dl1 = (e1 - r1f) * 0.25f;
        float dl2 = (e2 - r2f) * 0.25f;
        float dl3 = (e3 - r3f) * 0.25f;

        // q[m] = delta of the component with rank == 3-m  (ranks form a permutation)
        float q0 = (k0 == 3) ? dl0 : ((k1 == 3) ? dl1 : ((k2 == 3) ? dl2 : dl3));
        float q1 = (k0 == 2) ? dl0 : ((k1 == 2) ? dl1 : ((k2 == 2) ? dl2 : dl3));
        float q2 = (k0 == 1) ? dl0 : ((k1 == 1) ? dl1 : ((k2 == 1) ? dl2 : dl3));
        float q3 = (k0 == 0) ? dl0 : ((k1 == 0) ? dl1 : ((k2 == 0) ? dl2 : dl3));
        float wg0 = q0 + (1.0f - q3);
        float wg1 = q1 - q0;
        float wg2 = q2 - q1;
        float wg3 = q3 - q2;

        int i0 = (int)r0f, i1 = (int)r1f, i2 = (int)r2f;
        const unsigned P1 = 2654435761u, P2 = 805459861u;
        // vertex k: key_d = rem0_d + k - 4*(rank_d > 3-k), hash first 3 comps
        unsigned hA = (unsigned)i0 ^ ((unsigned)i1 * P1) ^ ((unsigned)i2 * P2);
        int b0 = i0 + 1 - ((k0 > 2) ? 4 : 0);
        int b1v = i1 + 1 - ((k1 > 2) ? 4 : 0);
        int b2v = i2 + 1 - ((k2 > 2) ? 4 : 0);
        unsigned hB = (unsigned)b0 ^ ((unsigned)b1v * P1) ^ ((unsigned)b2v * P2);
        int c0i = i0 + 2 - ((k0 > 1) ? 4 : 0);
        int c1i = i1 + 2 - ((k1 > 1) ? 4 : 0);
        int c2i = i2 + 2 - ((k2 > 1) ? 4 : 0);
        unsigned hC = (unsigned)c0i ^ ((unsigned)c1i * P1) ^ ((unsigned)c2i * P2);
        int e0i = i0 + 3 - ((k0 > 0) ? 4 : 0);
        int e1i = i1 + 3 - ((k1 > 0) ? 4 : 0);
        int e2i = i2 + 3 - ((k2 > 0) ? 4 : 0);
        unsigned hD = (unsigned)e0i ^ ((unsigned)e1i * P1) ^ ((unsigned)e2i * P2);

        const float2* tab = (const float2*)tables + (size_t)l * CAPM;
        float2 gA = tab[hA & (CAPM - 1)];
        float2 gB = tab[hB & (CAPM - 1)];
        float2 gC = tab[hC & (CAPM - 1)];
        float2 gD = tab[hD & (CAPM - 1)];

        float f0 = wg0 * gA.x + wg1 * gB.x + wg2 * gC.x + wg3 * gD.x;
        float f1 = wg0 * gA.y + wg1 * gB.y + wg2 * gC.y + wg3 * gD.y;
        f0 *= win;
        f1 *= win;

        const float* wr0 = w1 + (2 * l) * HID;
        const float* wr1 = wr0 + HID;
        #pragma unroll
        for (int j = 0; j < HID; j++)
            h1[j] = fmaf(f1, wr1[j], fmaf(f0, wr0[j], h1[j]));
    }

    // layer 2
    float g[HID];
    #pragma unroll
    for (int i = 0; i < HID; i++) g[i] = gelu_exact(h1[i]);
    float h2[HID];
    #pragma unroll
    for (int j = 0; j < HID; j++) h2[j] = b2[j];
    #pragma unroll
    for (int i = 0; i < HID; i++) {
        float gi = g[i];
        #pragma unroll
        for (int j = 0; j < HID; j++) h2[j] = fmaf(gi, w2[i * HID + j], h2[j]);
    }
    // layer 3 (reuse h1)
    #pragma unroll
    for (int i = 0; i < HID; i++) g[i] = gelu_exact(h2[i]);
    #pragma unroll
    for (int j = 0; j < HID; j++) h1[j] = b3[j];
    #pragma unroll
    for (int i = 0; i < HID; i++) {
        float gi = g[i];
        #pragma unroll
        for (int j = 0; j < HID; j++) h1[j] = fmaf(gi, w3[i * HID + j], h1[j]);
    }
    // layer 4: 33 outputs
    #pragma unroll
    for (int i = 0; i < HID; i++) g[i] = gelu_exact(h1[i]);
    float o[33];
    #pragma unroll
    for (int j = 0; j < 33; j++) o[j] = b4[j];
    #pragma unroll
    for (int i = 0; i < HID; i++) {
        float gi = g[i];
        #pragma unroll
        for (int j = 0; j < 33; j++) o[j] = fmaf(gi, w4[i * 33 + j], o[j]);
    }

    out[pid] = o[0];                              // sdf
    float* geo = out + N + (size_t)pid * 32;      // geom_feat (cols 1..32)
    #pragma unroll
    for (int j = 0; j < 32; j += 4) {
        float4 v = make_float4(o[1 + j], o[2 + j], o[3 + j], o[4 + j]);
        *reinterpret_cast<float4*>(geo + j) = v;
    }
}

extern "C" void kernel_launch(void* const* d_in, const int* in_sizes, int n_in,
                              void* d_out, int out_size, void* d_ws, size_t ws_size,
                              hipStream_t stream) {
    const float* points = (const float*)d_in[0];
    const int*   iter_p = (const int*)d_in[1];
    const float* tables = (const float*)d_in[2];
    const float* shifts = (const float*)d_in[3];
    const float* w1 = (const float*)d_in[4];
    const float* b1 = (const float*)d_in[5];
    const float* w2 = (const float*)d_in[6];
    const float* b2 = (const float*)d_in[7];
    const float* w3 = (const float*)d_in[8];
    const float* b3 = (const float*)d_in[9];
    const float* w4 = (const float*)d_in[10];
    const float* b4 = (const float*)d_in[11];
    float* out = (float*)d_out;
    float* ws  = (float*)d_ws;
    int N = in_sizes[0] / 3;

    init_consts<<<1, 64, 0, stream>>>(iter_p, ws);
    int block = 256;
    int grid = (N + block - 1) / block;
    sdf_fused<<<grid, block, 0, stream>>>(points, tables, shifts,
                                          w1, b1, w2, b2, w3, b3, w4, b4,
                                          ws, out, N);
}